// Round 1
// 723.079 us; speedup vs baseline: 1.0974x; 1.0974x over previous
//
#include <hip/hip_runtime.h>
#include <stdint.h>
#include <stddef.h>

// Grouped GEMM (MoE ragged_dot): C[T,N] fp32 = A[T,K] fp32 @ B[widx[s],:,:]^T
// V2 strategy: one-time fp32->bf16 conversion pre-pass into workspace
// (A 32MB + B 128MB = 160MB, fits 256MB L3), then an m97-structure GEMM:
// 128x128 tile, BK=32, 4 waves, global_load_lds width-16 staging into
// LINEAR LDS (gload_lds writes wave-uniform base + lane*16 -> layout must
// be linear), 2-barrier K-loop, MFMA 16x16x32 bf16, 4x4 frags/wave.
// Fallback to the previous (verified) fused-conversion kernel if ws_size
// is too small for the bf16 copies.

typedef __attribute__((ext_vector_type(8))) short short8;   // 8 x bf16
typedef __attribute__((ext_vector_type(4))) float floatx4;  // MFMA acc

constexpr int E_c = 8;
constexpr int T_c = 8192;
constexpr int K_c = 2048;
constexpr int N_c = 4096;
constexpr int BM = 128;
constexpr int BN = 128;
constexpr int BK = 32;                 // K per iteration (bf16 path)
constexpr int KSTEPS = K_c / BK;       // 64
constexpr int XTILES = T_c / BM + E_c; // 72 (upper bound incl. ragged pad)
constexpr int YTILES = N_c / BN;       // 32

// two fp32 -> packed bf16x2 (truncation; rel bias ~2^-9, threshold is 2%)
__device__ __forceinline__ uint32_t pack2(float lo, float hi) {
  union { float f; uint32_t u; } a, b;
  a.f = lo; b.f = hi;
  return __builtin_amdgcn_perm(b.u, a.u, 0x07060302u);
}

// ---------------------------------------------------------------------------
// Pre-pass: fp32 -> bf16 (truncation), 8 floats per thread-iter, grid-stride.
// ---------------------------------------------------------------------------
__global__ __launch_bounds__(256) void cvt_bf16_kernel(
    const float* __restrict__ src, ushort* __restrict__ dst, int n8) {
  int i = blockIdx.x * 256 + threadIdx.x;
  const int stride = gridDim.x * 256;
  for (; i < n8; i += stride) {
    const float4* p = (const float4*)src + (size_t)i * 2;
    float4 v0 = p[0], v1 = p[1];
    int4 o;
    o.x = pack2(v0.x, v0.y);
    o.y = pack2(v0.z, v0.w);
    o.z = pack2(v1.x, v1.y);
    o.w = pack2(v1.z, v1.w);
    ((int4*)dst)[i] = o;
  }
}

// ---------------------------------------------------------------------------
// Main GEMM on bf16 operands (m97 structure, grouped).
// ---------------------------------------------------------------------------
__device__ __forceinline__ void gload16(const ushort* g, ushort* l) {
  __builtin_amdgcn_global_load_lds(
      (const __attribute__((address_space(1))) unsigned int*)g,
      (__attribute__((address_space(3))) unsigned int*)l, 16, 0, 0);
}

__global__ __launch_bounds__(256) void grouped_gemm_bf16_kernel(
    const ushort* __restrict__ A, const ushort* __restrict__ B,
    const int* __restrict__ segp, const int* __restrict__ widx,
    float* __restrict__ C) {
  // Linear tiles (required by global_load_lds): [row][k], 64 B rows.
  __shared__ ushort As[BM * BK];  // 8 KB
  __shared__ ushort Bs[BN * BK];  // 8 KB

  const int t = threadIdx.x;

  // ---- XCD-aware tile remap: xcd = bid&7 owns y in [4*xcd, 4*xcd+4) ----
  const int bid = blockIdx.x;
  const int xcd = bid & 7;
  const int i = bid >> 3;        // 0..287
  const int yl = i / XTILES;     // 0..3
  const int x = i - yl * XTILES; // 0..71
  const int y = xcd * 4 + yl;

  // ---- segment scan: map x -> (segment, row0) ----
  int s = -1, r0i = 0, rendi = 0, acc_t = 0;
#pragma unroll
  for (int e = 0; e < E_c; ++e) {
    int pe = segp[e], pe1 = segp[e + 1];
    int nt = (pe1 - pe + BM - 1) >> 7;
    if (s < 0 && (x - acc_t) < nt) {
      s = e;
      r0i = pe + ((x - acc_t) << 7);
      rendi = pe1;
    }
    acc_t += nt;
  }
  if (s < 0) return;  // idle pad slot
  const int expert = widx[s];
  const int n0 = y * BN;

  // ---- staging map for global_load_lds ----
  // Wave w issue j covers LDS chunk c = j*4 + w (1024 B = rows c*16..c*16+15).
  // Lane l writes bytes [c*1024 + l*16, +16): row = c*16 + l/4, k16 = l%4.
  const int wave = t >> 6;
  const int lane = t & 63;
  const int rl = lane >> 2;  // row within 16-row chunk
  const int kq = lane & 3;   // 16B chunk within 64B row

  int ar0 = r0i + wave * 16 + rl;       // issue 0: rows 0..63 of tile
  int ar1 = ar0 + 64;                   // issue 1: rows 64..127
  if (ar0 > T_c - 1) ar0 = T_c - 1;     // ragged tail: garbage rows, masked store
  if (ar1 > T_c - 1) ar1 = T_c - 1;
  const ushort* Ag0 = A + (size_t)ar0 * K_c + kq * 8;
  const ushort* Ag1 = A + (size_t)ar1 * K_c + kq * 8;
  const ushort* Bg0 =
      B + ((size_t)expert * N_c + n0 + wave * 16 + rl) * K_c + kq * 8;
  const ushort* Bg1 = Bg0 + (size_t)64 * K_c;

  ushort* Al0 = As + wave * 512;         // wave-uniform LDS bases
  ushort* Al1 = As + 2048 + wave * 512;
  ushort* Bl0 = Bs + wave * 512;
  ushort* Bl1 = Bs + 2048 + wave * 512;

  // ---- fragment read indices (one ds_read_b128 per fragment) ----
  const int m16 = lane & 15;
  const int quad = lane >> 4;
  const int wm = (wave & 1) << 6;
  const int wn = (wave >> 1) << 6;
  int ia[4], ib[4];
#pragma unroll
  for (int q = 0; q < 4; ++q) {
    ia[q] = (wm + q * 16 + m16) * BK + quad * 8;
    ib[q] = (wn + q * 16 + m16) * BK + quad * 8;
  }

  floatx4 acc[4][4];
#pragma unroll
  for (int p = 0; p < 4; ++p)
#pragma unroll
    for (int q = 0; q < 4; ++q) acc[p][q] = (floatx4){0.f, 0.f, 0.f, 0.f};

  // ---- 2-barrier K loop (m97 structure; TLP across blocks hides drains) ----
#pragma unroll 1
  for (int kt = 0; kt < KSTEPS; ++kt) {
    __syncthreads();  // previous iter's frag reads done before overwrite
    gload16(Ag0, Al0);
    gload16(Ag1, Al1);
    gload16(Bg0, Bl0);
    gload16(Bg1, Bl1);
    Ag0 += BK; Ag1 += BK; Bg0 += BK; Bg1 += BK;
    __syncthreads();  // compiler emits vmcnt(0) drain -> tiles visible

    short8 aF[4], bF[4];
#pragma unroll
    for (int q = 0; q < 4; ++q) {
      aF[q] = *(const short8*)&As[ia[q]];
      bF[q] = *(const short8*)&Bs[ib[q]];
    }
#pragma unroll
    for (int p = 0; p < 4; ++p)
#pragma unroll
      for (int q = 0; q < 4; ++q)
        acc[p][q] = __builtin_amdgcn_mfma_f32_16x16x32_bf16(aF[p], bF[q],
                                                            acc[p][q], 0, 0, 0);
  }

  // ---- epilogue: C/D layout col=lane&15, row=quad*4+reg ----
#pragma unroll
  for (int p = 0; p < 4; ++p) {
    int growb = r0i + wm + p * 16 + quad * 4;
#pragma unroll
    for (int q = 0; q < 4; ++q) {
      int gcol = n0 + wn + q * 16 + m16;
#pragma unroll
      for (int rr = 0; rr < 4; ++rr) {
        int grow = growb + rr;
        if (grow < rendi) C[(size_t)grow * N_c + gcol] = acc[p][q][rr];
      }
    }
  }
}

// ---------------------------------------------------------------------------
// Fallback (previous verified kernel): fused fp32->bf16 staging, used only
// if ws_size is too small for the bf16 copies.
// ---------------------------------------------------------------------------
constexpr int LSTR = 5;  // LDS row stride in 16B chunks (4+1 pad)

__device__ __forceinline__ void cvt16(const float4* p, int4* c0, int4* c1) {
  c0->x = pack2(p[0].x, p[0].y); c0->y = pack2(p[0].z, p[0].w);
  c0->z = pack2(p[1].x, p[1].y); c0->w = pack2(p[1].z, p[1].w);
  c1->x = pack2(p[2].x, p[2].y); c1->y = pack2(p[2].z, p[2].w);
  c1->z = pack2(p[3].x, p[3].y); c1->w = pack2(p[3].z, p[3].w);
}

__global__ __launch_bounds__(256) void grouped_gemm_fallback(
    const float* __restrict__ A, const float* __restrict__ B,
    const int* __restrict__ segp, const int* __restrict__ widx,
    float* __restrict__ C) {
  __shared__ int4 As[BM * LSTR];
  __shared__ int4 Bs[BN * LSTR];

  const int t = threadIdx.x;
  const int bid = blockIdx.x;
  const int xcd = bid & 7;
  const int i = bid >> 3;
  const int yl = i / XTILES;
  const int x = i - yl * XTILES;
  const int y = xcd * 4 + yl;

  int s = -1, r0i = 0, rendi = 0, acc_t = 0;
#pragma unroll
  for (int e = 0; e < E_c; ++e) {
    int pe = segp[e], pe1 = segp[e + 1];
    int nt = (pe1 - pe + BM - 1) >> 7;
    if (s < 0 && (x - acc_t) < nt) {
      s = e;
      r0i = pe + ((x - acc_t) << 7);
      rendi = pe1;
    }
    acc_t += nt;
  }
  if (s < 0) return;
  const int expert = widx[s];
  const int n0 = y * BN;

  const int r = t >> 1;
  const int h = t & 1;
  int arow = r0i + r;
  if (arow > T_c - 1) arow = T_c - 1;
  const float* Abase = A + (size_t)arow * K_c + h * 16;
  const float* Bbase = B + ((size_t)expert * N_c + n0 + r) * K_c + h * 16;
  const int wI = r * LSTR + 2 * h;

  const int lane = t & 63;
  const int wave = t >> 6;
  const int m16 = lane & 15;
  const int quad = lane >> 4;
  const int wm = (wave & 1) << 6;
  const int wn = (wave >> 1) << 6;
  int ia[4], ib[4];
#pragma unroll
  for (int q = 0; q < 4; ++q) {
    ia[q] = (wm + q * 16 + m16) * LSTR + quad;
    ib[q] = (wn + q * 16 + m16) * LSTR + quad;
  }

  floatx4 acc[4][4];
#pragma unroll
  for (int p = 0; p < 4; ++p)
#pragma unroll
    for (int q = 0; q < 4; ++q) acc[p][q] = (floatx4){0.f, 0.f, 0.f, 0.f};

  float4 pa[4], pb[4];
#pragma unroll
  for (int j = 0; j < 4; ++j) {
    pa[j] = ((const float4*)Abase)[j];
    pb[j] = ((const float4*)Bbase)[j];
  }

#pragma unroll 1
  for (int kt = 0; kt < KSTEPS * BK / 32; ++kt) {
    __syncthreads();
    int4 a0, a1, b0, b1;
    cvt16(pa, &a0, &a1);
    cvt16(pb, &b0, &b1);
    As[wI] = a0; As[wI + 1] = a1;
    Bs[wI] = b0; Bs[wI + 1] = b1;
    __syncthreads();

    const int knext = (kt + 1 < 64) ? kt + 1 : 63;
    const float* an = Abase + knext * 32;
    const float* bn = Bbase + knext * 32;
#pragma unroll
    for (int j = 0; j < 4; ++j) {
      pa[j] = ((const float4*)an)[j];
      pb[j] = ((const float4*)bn)[j];
    }

    short8 aF[4], bF[4];
#pragma unroll
    for (int q = 0; q < 4; ++q) {
      aF[q] = *(const short8*)&As[ia[q]];
      bF[q] = *(const short8*)&Bs[ib[q]];
    }
#pragma unroll
    for (int p = 0; p < 4; ++p)
#pragma unroll
      for (int q = 0; q < 4; ++q)
        acc[p][q] = __builtin_amdgcn_mfma_f32_16x16x32_bf16(aF[p], bF[q],
                                                            acc[p][q], 0, 0, 0);
  }

#pragma unroll
  for (int p = 0; p < 4; ++p) {
    int growb = r0i + wm + p * 16 + quad * 4;
#pragma unroll
    for (int q = 0; q < 4; ++q) {
      int gcol = n0 + wn + q * 16 + m16;
#pragma unroll
      for (int rr = 0; rr < 4; ++rr) {
        int grow = growb + rr;
        if (grow < rendi) C[(size_t)grow * N_c + gcol] = acc[p][q][rr];
      }
    }
  }
}

// ---------------------------------------------------------------------------
extern "C" void kernel_launch(void* const* d_in, const int* in_sizes, int n_in,
                              void* d_out, int out_size, void* d_ws, size_t ws_size,
                              hipStream_t stream) {
  const float* A = (const float*)d_in[0];
  const float* B = (const float*)d_in[1];
  const int* segp = (const int*)d_in[5];
  const int* widx = (const int*)d_in[6];
  float* C = (float*)d_out;

  const size_t abytes = (size_t)T_c * K_c * 2;        // 32 MB bf16 A
  const size_t bbytes = (size_t)E_c * N_c * K_c * 2;  // 128 MB bf16 B

  if (ws_size >= abytes + bbytes) {
    ushort* Abf = (ushort*)d_ws;
    ushort* Bbf = Abf + (size_t)T_c * K_c;
    cvt_bf16_kernel<<<2048, 256, 0, stream>>>(A, Abf, T_c * K_c / 8);
    cvt_bf16_kernel<<<2048, 256, 0, stream>>>(B, Bbf, E_c * N_c * K_c / 8);
    grouped_gemm_bf16_kernel<<<dim3(XTILES * YTILES), 256, 0, stream>>>(
        Abf, Bbf, segp, widx, C);
  } else {
    grouped_gemm_fallback<<<dim3(XTILES * YTILES), 256, 0, stream>>>(
        A, B, segp, widx, C);
  }
}